// Round 1
// baseline (261.442 us; speedup 1.0000x reference)
//
#include <hip/hip_runtime.h>
#include <hip/hip_bf16.h>
#include <stdint.h>

typedef __attribute__((ext_vector_type(8))) short bf16x8;
typedef __attribute__((ext_vector_type(4))) float f32x4;

#define B_SZ 2048
#define L_SZ 200
#define D_SZ 128
#define NROWS (B_SZ * L_SZ)   // 409600
#define NTILES (NROWS / 16)   // 25600

__device__ __forceinline__ short f2bf(float f) {
    union { float f; uint32_t u; } v; v.f = f;
    uint32_t u = v.u;
    u += 0x7FFFu + ((u >> 16) & 1u);   // RNE
    return (short)(u >> 16);
}
__device__ __forceinline__ float bf2f(short s) {
    union { uint32_t u; float f; } v; v.u = ((uint32_t)(uint16_t)s) << 16;
    return v.f;
}
__device__ __forceinline__ float sigm(float x) {
    return 1.0f / (1.0f + __expf(-x));
}

// ---------------- K0: weight prep + stat zeroing ----------------
// A' = W1a + W1c (f32, 128x128)
// Wf: [B'; C'] (256x128) pre-swizzled into MFMA B-frag blobs:
//   frag (ct 0..7, kt 0..7): lane l, j0..7 -> Wcomb[kt*32 + (l>>4)*8 + j][ct*16 + (l&15)]
// W2f: same for W2 (128x32): ct 0..1, kt 0..3.
__global__ void k0_prep(const float* __restrict__ W1, const float* __restrict__ W2,
                        float* __restrict__ Aprime, ushort* __restrict__ Wf,
                        ushort* __restrict__ W2f, float* __restrict__ stats)
{
    const int total = 16384 + 32768 + 4096 + 512;
    for (int i = blockIdx.x * blockDim.x + threadIdx.x; i < total; i += gridDim.x * blockDim.x) {
        if (i < 16384) {
            int r = i >> 7, c = i & 127;
            Aprime[i] = W1[r * 128 + c] + W1[(256 + r) * 128 + c];
        } else if (i < 16384 + 32768) {
            int f = i - 16384;
            int j = f & 7, l = (f >> 3) & 63, kt = (f >> 9) & 7, ct = f >> 12;
            int kk = kt * 32 + ((l >> 4) << 3) + j;
            int col = (ct << 4) + (l & 15);
            float v = (kk < 128) ? (W1[(128 + kk) * 128 + col] - W1[(256 + kk) * 128 + col])
                                 : W1[(384 + (kk - 128)) * 128 + col];
            Wf[f] = (ushort)f2bf(v);
        } else if (i < 16384 + 32768 + 4096) {
            int f = i - (16384 + 32768);
            int j = f & 7, l = (f >> 3) & 63, kt = (f >> 9) & 3, ct = f >> 11;
            int kk = kt * 32 + ((l >> 4) << 3) + j;
            int col = (ct << 4) + (l & 15);
            W2f[f] = (ushort)f2bf(W2[kk * 32 + col]);
        } else {
            stats[i - (16384 + 32768 + 4096)] = 0.0f;  // 512 floats: stats1(256) + stats2(256)
        }
    }
}

// ---------------- K1: qA[b][c] = q[b]@A' + b1  (tiny f32 GEMM) ----------------
__global__ void k1_qA(const float* __restrict__ q, const float* __restrict__ Aprime,
                      const float* __restrict__ b1, float* __restrict__ qA)
{
    __shared__ float qs[128];
    int b = blockIdx.x, c = threadIdx.x;
    qs[c] = q[b * 128 + c];
    __syncthreads();
    float acc = b1[c];
    #pragma unroll 8
    for (int r = 0; r < 128; ++r) acc += qs[r] * Aprime[r * 128 + c];
    qA[b * 128 + c] = acc;
}

// ---------------- K2: z1 = k@B' + (q*k)@C' + qA ; per-channel sum/sumsq ----------------
// 1-wave blocks. half = bid&1 picks col half (persistent B-frags, 4ct x 8kt = 128 VGPR).
// Wave tile: 16 rows x 64 cols; grid-stride over 25600 row-tiles.
__global__ void __launch_bounds__(64, 2) k2_main(
    const float* __restrict__ query, const float* __restrict__ keys,
    const float* __restrict__ qA, const ushort* __restrict__ Wf,
    ushort* __restrict__ z1, float* __restrict__ stats1)
{
    const int lane = threadIdx.x;
    const int half = blockIdx.x & 1;
    const int colbase = half * 64;
    const int r15 = lane & 15, g = lane >> 4;

    bf16x8 bfr[4][8];
    #pragma unroll
    for (int ctl = 0; ctl < 4; ++ctl)
        #pragma unroll
        for (int kt = 0; kt < 8; ++kt) {
            int ct = half * 4 + ctl;
            bfr[ctl][kt] = *(const bf16x8*)(Wf + ((size_t)(ct * 8 + kt) * 64 + lane) * 8);
        }

    float ssum[4] = {0, 0, 0, 0}, ssq[4] = {0, 0, 0, 0};

    for (int rt = (blockIdx.x >> 1); rt < NTILES; rt += (gridDim.x >> 1)) {
        int rowA = rt * 16 + r15;
        int bA = rowA / 200;
        const float* kp = keys + (size_t)rowA * 128 + g * 8;
        const float* qp = query + (size_t)bA * 128 + g * 8;

        f32x4 kv[4][2], qv[4][2];
        #pragma unroll
        for (int kt = 0; kt < 4; ++kt) {
            kv[kt][0] = *(const f32x4*)(kp + kt * 32);
            kv[kt][1] = *(const f32x4*)(kp + kt * 32 + 4);
            qv[kt][0] = *(const f32x4*)(qp + kt * 32);
            qv[kt][1] = *(const f32x4*)(qp + kt * 32 + 4);
        }
        bf16x8 afr[8];
        #pragma unroll
        for (int kt = 0; kt < 4; ++kt) {
            bf16x8 ak, ac;
            #pragma unroll
            for (int h = 0; h < 2; ++h)
                #pragma unroll
                for (int j = 0; j < 4; ++j) {
                    float kf = kv[kt][h][j];
                    float qf = qv[kt][h][j];
                    ak[h * 4 + j] = f2bf(kf);
                    ac[h * 4 + j] = f2bf(qf * kf);
                }
            afr[kt] = ak;
            afr[4 + kt] = ac;
        }
        f32x4 acc[4];
        #pragma unroll
        for (int ctl = 0; ctl < 4; ++ctl) {
            acc[ctl] = (f32x4){0, 0, 0, 0};
            #pragma unroll
            for (int kt = 0; kt < 8; ++kt)
                acc[ctl] = __builtin_amdgcn_mfma_f32_16x16x32_bf16(afr[kt], bfr[ctl][kt], acc[ctl], 0, 0, 0);
        }
        int rowC = rt * 16 + g * 4;
        #pragma unroll
        for (int j = 0; j < 4; ++j) {
            int row = rowC + j;
            int bC = row / 200;
            #pragma unroll
            for (int ctl = 0; ctl < 4; ++ctl) {
                int col = colbase + ctl * 16 + r15;
                float v = acc[ctl][j] + qA[bC * 128 + col];
                ssum[ctl] += v;
                ssq[ctl] += v * v;
                z1[(size_t)row * 128 + col] = (ushort)f2bf(v);
            }
        }
    }
    #pragma unroll
    for (int ctl = 0; ctl < 4; ++ctl) {
        float s = ssum[ctl], q2 = ssq[ctl];
        s += __shfl_xor(s, 16); s += __shfl_xor(s, 32);
        q2 += __shfl_xor(q2, 16); q2 += __shfl_xor(q2, 32);
        if (g == 0) {
            int col = colbase + ctl * 16 + r15;
            atomicAdd(&stats1[col], s);
            atomicAdd(&stats1[128 + col], q2);
        }
    }
}

// ---------------- K3/K5: finalize stats -> rstd, bias0 = -m*rstd ----------------
__global__ void k_fin(const float* __restrict__ raw, float* __restrict__ fin, int nch)
{
    int c = threadIdx.x;
    if (c >= nch) return;
    float n = (float)NROWS;
    float m = raw[c] / n;
    float v = raw[nch + c] / n - m * m;
    float r = rsqrtf(v + 1e-8f);
    fin[c] = r;
    fin[nch + c] = -m * r;
}

// ---------------- K4: h1 = dice(z1); z2 = h1@W2 + b2; stats2 ----------------
__global__ void __launch_bounds__(64, 2) k4_z2(
    const ushort* __restrict__ z1, const ushort* __restrict__ W2f,
    const float* __restrict__ fin1, const float* __restrict__ alpha1,
    const float* __restrict__ b2, float* __restrict__ z2, float* __restrict__ stats2)
{
    const int lane = threadIdx.x, r15 = lane & 15, g = lane >> 4;
    bf16x8 bfr[2][4];
    #pragma unroll
    for (int ct = 0; ct < 2; ++ct)
        #pragma unroll
        for (int kt = 0; kt < 4; ++kt)
            bfr[ct][kt] = *(const bf16x8*)(W2f + ((size_t)(ct * 4 + kt) * 64 + lane) * 8);

    // per-lane channel params (channels fixed per lane across all tiles)
    float rstd[4][8], bias0[4][8], alp[4][8];
    #pragma unroll
    for (int kt = 0; kt < 4; ++kt)
        #pragma unroll
        for (int j = 0; j < 8; ++j) {
            int c = kt * 32 + g * 8 + j;
            rstd[kt][j] = fin1[c];
            bias0[kt][j] = fin1[128 + c];
            alp[kt][j] = alpha1[c];
        }
    float b2v[2] = { b2[r15], b2[16 + r15] };
    float ssum[2] = {0, 0}, ssq[2] = {0, 0};

    for (int rt = blockIdx.x; rt < NTILES; rt += gridDim.x) {
        int rowA = rt * 16 + r15;
        bf16x8 afr[4];
        #pragma unroll
        for (int kt = 0; kt < 4; ++kt) {
            bf16x8 zv = *(const bf16x8*)(z1 + (size_t)rowA * 128 + kt * 32 + g * 8);
            bf16x8 hv;
            #pragma unroll
            for (int j = 0; j < 8; ++j) {
                float z = bf2f(zv[j]);
                float zh = z * rstd[kt][j] + bias0[kt][j];
                float p = sigm(zh);
                float t = p + (1.0f - p) * alp[kt][j];
                hv[j] = f2bf(z * t);
            }
            afr[kt] = hv;
        }
        f32x4 acc[2];
        #pragma unroll
        for (int ct = 0; ct < 2; ++ct) {
            acc[ct] = (f32x4){0, 0, 0, 0};
            #pragma unroll
            for (int kt = 0; kt < 4; ++kt)
                acc[ct] = __builtin_amdgcn_mfma_f32_16x16x32_bf16(afr[kt], bfr[ct][kt], acc[ct], 0, 0, 0);
        }
        int rowC = rt * 16 + g * 4;
        #pragma unroll
        for (int j = 0; j < 4; ++j) {
            int row = rowC + j;
            #pragma unroll
            for (int ct = 0; ct < 2; ++ct) {
                float v = acc[ct][j] + b2v[ct];
                ssum[ct] += v;
                ssq[ct] += v * v;
                z2[(size_t)row * 32 + ct * 16 + r15] = v;
            }
        }
    }
    #pragma unroll
    for (int ct = 0; ct < 2; ++ct) {
        float s = ssum[ct], q2 = ssq[ct];
        s += __shfl_xor(s, 16); s += __shfl_xor(s, 32);
        q2 += __shfl_xor(q2, 16); q2 += __shfl_xor(q2, 32);
        if (g == 0) {
            int col = ct * 16 + r15;
            atomicAdd(&stats2[col], s);
            atomicAdd(&stats2[32 + col], q2);
        }
    }
}

// ---------------- K6: score = dice(z2)@Wd + bd, mask, pool over L ----------------
__global__ void __launch_bounds__(256) k6_score_pool(
    const float* __restrict__ z2, const float* __restrict__ keys,
    const int* __restrict__ keys_len, const float* __restrict__ fin2,
    const float* __restrict__ alpha2, const float* __restrict__ Wd,
    const float* __restrict__ bd, float* __restrict__ out)
{
    __shared__ float pp[129];      // [0..31] rstd2, [32..63] bias2, [64..95] alpha2, [96..127] Wd, [128] bd
    __shared__ float sc[200];
    __shared__ float part[2][128];
    int b = blockIdx.x, t = threadIdx.x;
    if (t < 64) pp[t] = fin2[t];
    else if (t < 96) pp[t] = alpha2[t - 64];
    else if (t < 128) pp[t] = Wd[t - 96];
    else if (t == 128) pp[128] = bd[0];
    __syncthreads();

    int klen = keys_len[b];
    if (t < 200) {
        const float* zp = z2 + ((size_t)b * 200 + t) * 32;
        f32x4 zr[8];
        #pragma unroll
        for (int i = 0; i < 8; ++i) zr[i] = ((const f32x4*)zp)[i];
        float s = pp[128];
        #pragma unroll
        for (int c = 0; c < 32; ++c) {
            float z = zr[c >> 2][c & 3];
            float zh = z * pp[c] + pp[32 + c];
            float p = sigm(zh);
            float h = z * (p + (1.0f - p) * pp[64 + c]);
            s += h * pp[96 + c];
        }
        sc[t] = (t < klen) ? s : 0.0f;
    }
    __syncthreads();

    int c = t & 127, prt = t >> 7;
    const float* kp = keys + ((size_t)b * 200 + prt * 100) * 128 + c;
    float acc = 0.0f;
    #pragma unroll 4
    for (int l = 0; l < 100; ++l) acc += sc[prt * 100 + l] * kp[(size_t)l * 128];
    part[prt][c] = acc;
    __syncthreads();
    if (t < 128) out[(size_t)b * 128 + t] = part[0][t] + part[1][t];
}

// ---------------- host launch ----------------
extern "C" void kernel_launch(void* const* d_in, const int* in_sizes, int n_in,
                              void* d_out, int out_size, void* d_ws, size_t ws_size,
                              hipStream_t stream) {
    const float* query    = (const float*)d_in[0];
    const float* keys     = (const float*)d_in[1];
    const int*   keys_len = (const int*)d_in[2];
    const float* W1       = (const float*)d_in[3];
    const float* b1       = (const float*)d_in[4];
    const float* alpha1   = (const float*)d_in[5];
    const float* W2       = (const float*)d_in[6];
    const float* b2       = (const float*)d_in[7];
    const float* alpha2   = (const float*)d_in[8];
    const float* Wd       = (const float*)d_in[9];
    const float* bd       = (const float*)d_in[10];
    float* out = (float*)d_out;

    char* ws = (char*)d_ws;
    ushort* z1     = (ushort*)(ws);                          // 104857600 B
    float*  z2     = (float*)(ws + 104857600);               // 52428800 B
    float*  qA     = (float*)(ws + 157286400);               // 1048576 B
    float*  Aprime = (float*)(ws + 158334976);               // 65536 B
    ushort* Wf     = (ushort*)(ws + 158400512);              // 65536 B
    ushort* W2f    = (ushort*)(ws + 158466048);              // 8192 B
    float*  stats  = (float*)(ws + 158474240);               // 2048 B (512 f32)
    float*  fin1   = (float*)(ws + 158476288);               // 1024 B
    float*  fin2   = (float*)(ws + 158477312);               // 256 B

    k0_prep<<<128, 256, 0, stream>>>(W1, W2, Aprime, Wf, W2f, stats);
    k1_qA<<<B_SZ, 128, 0, stream>>>(query, Aprime, b1, qA);
    k2_main<<<2048, 64, 0, stream>>>(query, keys, qA, Wf, z1, stats);
    k_fin<<<1, 128, 0, stream>>>(stats, fin1, 128);
    k4_z2<<<1600, 64, 0, stream>>>(z1, W2f, fin1, alpha1, b2, z2, stats + 256);
    k_fin<<<1, 32, 0, stream>>>(stats + 256, fin2, 32);
    k6_score_pool<<<B_SZ, 256, 0, stream>>>(z2, keys, keys_len, fin2, alpha2, Wd, bd, out);
}